// Round 6
// baseline (222.786 us; speedup 1.0000x reference)
//
#include <hip/hip_runtime.h>

#define NVOX 200000
#define KOFF 27
#define CIN 16
#define CMID 32
#define COUT 32
#define EPSBN 1e-3f
#define PD1 8   // conv1 pipeline depth (proven)
#define PD2 6   // conv2 pipeline depth (PD=10 spilled in R4)

typedef _Float16 f16x8 __attribute__((ext_vector_type(8)));
typedef _Float16 f16x4 __attribute__((ext_vector_type(4)));
typedef float f32x16 __attribute__((ext_vector_type(16)));

// ws layout (bytes):
//   [0, 21,600,000)              gatherT int32[KOFF][NVOX]  (-1 = none; gap-filled in k_build)
//   [21,600,000, 34,400,064)     x1h fp16[(NVOX+1)][32]  (conv1 RAW out; BN1 applied on the fly in conv2)
//   [34,400,064, 40,800,096)     featsh fp16[(NVOX+1)][16] (row NVOX = zeros)
//   [40,800,096, 40,827,744)     WB1 fp16[27][64][8]   B-frags for 32x32x16 (K=16=CIN)
//   [40,827,744, 40,883,040)     WB2 fp16[27][2][64][8] B-frags (K=32 split in 2)
//   [40,883,040, +512)           stats: sums1[64] | sums2[64]
#define OFF_X1H 21600000
#define OFF_FH  34400064
#define OFF_WB1 40800096
#define OFF_WB2 40827744
#define OFF_ST  40883040

// One pass: rulebook -> gatherT (-1 gap fill), feats->fp16, weight B-frags,
// zero rows, stats zeroing. rule_out ascending within each k; padding dst = NVOX.
// (R5's init+scatter split measured ~2us slower; monolithic gap-fill restored.)
__global__ __launch_bounds__(256) void k_build(const int* __restrict__ rule_in,
                                               const int* __restrict__ rule_out,
                                               const float* __restrict__ feats,
                                               const float* __restrict__ W1,
                                               const float* __restrict__ W2,
                                               int* __restrict__ gatherT,
                                               _Float16* __restrict__ featsh,
                                               _Float16* __restrict__ WB1,
                                               _Float16* __restrict__ WB2,
                                               _Float16* __restrict__ x1h,
                                               float* __restrict__ stats) {
  int e = blockIdx.x * 256 + threadIdx.x;
  if (e < KOFF * NVOX) {
    int k = e / NVOX;
    int pos = e - k * NVOX;
    int dst = rule_out[e];
    int ndst = (pos == NVOX - 1) ? NVOX : rule_out[e + 1];
    int* __restrict__ gk = gatherT + k * NVOX;
    if (dst < NVOX) {
      gk[dst] = rule_in[e];
      if (pos == 0) {
        for (int d = 0; d < dst; ++d) gk[d] = -1;
      }
      for (int d = dst + 1; d < ndst; ++d) gk[d] = -1;
    }
  }
  if (e < NVOX * CIN / 4) {
    float4 f = ((const float4*)feats)[e];
    f16x4 h = {(_Float16)f.x, (_Float16)f.y, (_Float16)f.z, (_Float16)f.w};
    ((f16x4*)featsh)[e] = h;
  }
  if (e < KOFF * 512) {  // WB1: lane l holds W1[k][kk=(l>>5)*8+j][n=l&31]
    int j = e & 7, l = (e >> 3) & 63, k = e >> 9;
    int kk = ((l >> 5) << 3) + j;
    int n = l & 31;
    WB1[e] = (_Float16)W1[(k * CIN + kk) * CMID + n];
  }
  if (e < KOFF * 1024) {  // WB2: f selects K-half
    int j = e & 7, l = (e >> 3) & 63, f = (e >> 9) & 1, k = e >> 10;
    int kk = (f << 4) + ((l >> 5) << 3) + j;
    int n = l & 31;
    WB2[e] = (_Float16)W2[(k * CMID + kk) * COUT + n];
  }
  if (e < CIN) featsh[(size_t)NVOX * CIN + e] = (_Float16)0.f;
  if (e < CMID) x1h[(size_t)NVOX * CMID + e] = (_Float16)0.f;
  if (e < 128) stats[e] = 0.f;
}

// conv1: 32 rows/wave, 1 MFMA (32x32x16, K=16=CIN) per offset.
// Depth-PD1 explicit pipeline; invalid neighbors read the zero row. Fused BN1 stats.
__global__ __launch_bounds__(512, 4) void k_conv1m(const _Float16* __restrict__ featsh,
                                                   const int* __restrict__ gatherT,
                                                   const uint4* __restrict__ WB1,
                                                   _Float16* __restrict__ x1h,
                                                   float* __restrict__ gsums) {
  __shared__ uint4 wlds[KOFF * 64];  // 27,648 B
  __shared__ float lsum[64];
  int tid = threadIdx.x;
  for (int i = tid; i < KOFF * 64; i += 512) wlds[i] = WB1[i];
  if (tid < 64) lsum[tid] = 0.f;
  __syncthreads();

  int lane = tid & 63, wave = tid >> 6;
  int m = lane & 31, h = lane >> 5;
  int rowbase = blockIdx.x * 256 + wave * 32;
  int row = rowbase + m;
  int rowc = (row < NVOX) ? row : (NVOX - 1);

  int idx[KOFF];
#pragma unroll
  for (int k = 0; k < KOFF; ++k) idx[k] = gatherT[k * NVOX + rowc];

  f16x8 A[PD1];
#pragma unroll
  for (int p = 0; p < PD1; ++p) {
    unsigned s = ((unsigned)idx[p] < (unsigned)NVOX) ? (unsigned)idx[p] : (unsigned)NVOX;
    A[p] = *(const f16x8*)(featsh + (size_t)s * CIN + (h << 3));
  }

  f32x16 c;
#pragma unroll
  for (int i = 0; i < 16; ++i) c[i] = 0.f;

#pragma unroll
  for (int k = 0; k < KOFF; ++k) {
    f16x8 a = A[k % PD1];
    if (k + PD1 < KOFF) {
      unsigned s = ((unsigned)idx[k + PD1] < (unsigned)NVOX) ? (unsigned)idx[k + PD1] : (unsigned)NVOX;
      A[k % PD1] = *(const f16x8*)(featsh + (size_t)s * CIN + (h << 3));
    }
    f16x8 b = ((const f16x8*)wlds)[k * 64 + lane];
    c = __builtin_amdgcn_mfma_f32_32x32x16_f16(a, b, c, 0, 0, 0);
  }

  // C layout: col = lane&31 (= channel m), row = (r&3) + 8*(r>>2) + 4*h
  float s0 = 0.f, q0 = 0.f;
#pragma unroll
  for (int r = 0; r < 16; ++r) {
    int grow = rowbase + (r & 3) + ((r >> 2) << 3) + (h << 2);
    float mk = (grow < NVOX) ? 1.f : 0.f;
    float v = c[r] * mk;
    s0 += v; q0 += v * v;
    if (grow < NVOX) x1h[(size_t)grow * CMID + m] = (_Float16)c[r];
  }
  s0 += __shfl_xor(s0, 32, 64);
  q0 += __shfl_xor(q0, 32, 64);
  if (lane < 32) {
    atomicAdd(&lsum[m], s0);
    atomicAdd(&lsum[32 + m], q0);
  }
  __syncthreads();
  if (tid < 64) atomicAdd(&gsums[tid], lsum[tid]);
}

// conv2: 32 rows/wave, 2 MFMAs (K=32) per offset, RAW x1h input with BN1+ReLU
// applied on the fly (packed fp16 fma/max). Invalid neighbors: load row 0, zero
// at consume time. NO LDS weight staging this round: B-frags read directly from
// the 55 KB global WB2 table (L1/L2-hot, identical addresses across all waves,
// contiguous 1 KB/wave per read). Removes the 55.3 KB LDS cap (2 blocks/CU ->
// thread-capped 4), the 3456-load staging prologue, and its barrier. Tests the
// last un-isolated binding-constraint candidate; if dur stays ~54 us, conv2 is
// at the per-CU random-cacheline fill floor (~2.2M lines, ~10 B/cy/CU).
__global__ __launch_bounds__(512, 4) void k_conv2m(const _Float16* __restrict__ x1h,
                                                   const int* __restrict__ gatherT,
                                                   const uint4* __restrict__ WB2,
                                                   float* __restrict__ out,
                                                   float* __restrict__ gsums,
                                                   const float* __restrict__ sums1,
                                                   const float* __restrict__ gamma1,
                                                   const float* __restrict__ beta1) {
  __shared__ float lsum[64];
  int tid = threadIdx.x;
  if (tid < 64) lsum[tid] = 0.f;

  int lane = tid & 63, wave = tid >> 6;
  int m = lane & 31, h = lane >> 5;

  // BN1 scale/shift for this lane's 16 input channels: c0 = h*8.. (A0 slice),
  // c1 = 16 + h*8.. (A1 slice). fp32 finalize, fp16 apply.
  f16x8 scv0, shv0, scv1, shv1;
  {
    const float inv_n = 1.0f / (float)NVOX;
    int c0 = h << 3;
#pragma unroll
    for (int i = 0; i < 8; ++i) {
      int ca = c0 + i, cb = 16 + c0 + i;
      float mua = sums1[ca] * inv_n;
      float vara = sums1[32 + ca] * inv_n - mua * mua;
      float sa = gamma1[ca] * rsqrtf(vara + EPSBN);
      scv0[i] = (_Float16)sa;
      shv0[i] = (_Float16)(beta1[ca] - mua * sa);
      float mub = sums1[cb] * inv_n;
      float varb = sums1[32 + cb] * inv_n - mub * mub;
      float sb = gamma1[cb] * rsqrtf(varb + EPSBN);
      scv1[i] = (_Float16)sb;
      shv1[i] = (_Float16)(beta1[cb] - mub * sb);
    }
  }
  __syncthreads();  // lsum zero-init visible before epilogue atomics

  int rowbase = blockIdx.x * 256 + wave * 32;
  int row = rowbase + m;
  int rowc = (row < NVOX) ? row : (NVOX - 1);

  int idx[KOFF];
#pragma unroll
  for (int k = 0; k < KOFF; ++k) idx[k] = gatherT[k * NVOX + rowc];

  f16x8 A0[PD2], A1[PD2];
#pragma unroll
  for (int p = 0; p < PD2; ++p) {
    unsigned s = ((unsigned)idx[p] < (unsigned)NVOX) ? (unsigned)idx[p] : 0u;
    const _Float16* rp = x1h + (size_t)s * CMID + (h << 3);
    A0[p] = *(const f16x8*)rp;
    A1[p] = *(const f16x8*)(rp + 16);
  }

  f32x16 c;
#pragma unroll
  for (int i = 0; i < 16; ++i) c[i] = 0.f;

  const f16x8 zero8 = (f16x8)(_Float16)0.f;
  const f16x8* __restrict__ WBv = (const f16x8*)WB2;

#pragma unroll
  for (int k = 0; k < KOFF; ++k) {
    f16x8 a0r = A0[k % PD2], a1r = A1[k % PD2];
    if (k + PD2 < KOFF) {
      unsigned s = ((unsigned)idx[k + PD2] < (unsigned)NVOX) ? (unsigned)idx[k + PD2] : 0u;
      const _Float16* rp = x1h + (size_t)s * CMID + (h << 3);
      A0[k % PD2] = *(const f16x8*)rp;
      A1[k % PD2] = *(const f16x8*)(rp + 16);
    }
    bool valid = (unsigned)idx[k] < (unsigned)NVOX;
    // BN1 + ReLU in packed fp16, then zero invalid rows
    f16x8 t0 = a0r * scv0 + shv0;
    f16x8 t1 = a1r * scv1 + shv1;
    t0 = __builtin_elementwise_max(t0, zero8);
    t1 = __builtin_elementwise_max(t1, zero8);
    f16x8 a0 = valid ? t0 : zero8;
    f16x8 a1 = valid ? t1 : zero8;
    f16x8 b0 = WBv[(k * 2 + 0) * 64 + lane];
    f16x8 b1 = WBv[(k * 2 + 1) * 64 + lane];
    c = __builtin_amdgcn_mfma_f32_32x32x16_f16(a0, b0, c, 0, 0, 0);
    c = __builtin_amdgcn_mfma_f32_32x32x16_f16(a1, b1, c, 0, 0, 0);
  }

  float s0 = 0.f, q0 = 0.f;
#pragma unroll
  for (int r = 0; r < 16; ++r) {
    int grow = rowbase + (r & 3) + ((r >> 2) << 3) + (h << 2);
    float mk = (grow < NVOX) ? 1.f : 0.f;
    float v = c[r] * mk;
    s0 += v; q0 += v * v;
    if (grow < NVOX) out[(size_t)grow * COUT + m] = c[r];
  }
  s0 += __shfl_xor(s0, 32, 64);
  q0 += __shfl_xor(q0, 32, 64);
  if (lane < 32) {
    atomicAdd(&lsum[m], s0);
    atomicAdd(&lsum[32 + m], q0);
  }
  __syncthreads();
  if (tid < 64) atomicAdd(&gsums[tid], lsum[tid]);
}

// BN2+ReLU in place on fp32 out, finalize fused
__global__ __launch_bounds__(256) void k_bnrelu2(float* __restrict__ out,
                                                 const float* __restrict__ sums,
                                                 const float* __restrict__ gamma,
                                                 const float* __restrict__ beta) {
  int t = blockIdx.x * 256 + threadIdx.x;
  if (t >= NVOX * COUT / 4) return;
  int c = (t & 7) * 4;
  const float inv_n = 1.0f / (float)NVOX;
  float sc[4], sh[4];
#pragma unroll
  for (int i = 0; i < 4; ++i) {
    float mu = sums[c + i] * inv_n;
    float var = sums[32 + c + i] * inv_n - mu * mu;
    float s = gamma[c + i] * rsqrtf(var + EPSBN);
    sc[i] = s; sh[i] = beta[c + i] - mu * s;
  }
  float4* p = (float4*)out + t;
  float4 v = *p;
  v.x = fmaxf(fmaf(v.x, sc[0], sh[0]), 0.f);
  v.y = fmaxf(fmaf(v.y, sc[1], sh[1]), 0.f);
  v.z = fmaxf(fmaf(v.z, sc[2], sh[2]), 0.f);
  v.w = fmaxf(fmaf(v.w, sc[3], sh[3]), 0.f);
  *p = v;
}

extern "C" void kernel_launch(void* const* d_in, const int* in_sizes, int n_in,
                              void* d_out, int out_size, void* d_ws, size_t ws_size,
                              hipStream_t stream) {
  const float* feats  = (const float*)d_in[0];
  const float* W1     = (const float*)d_in[1];
  const float* gamma1 = (const float*)d_in[2];
  const float* beta1  = (const float*)d_in[3];
  const float* W2     = (const float*)d_in[4];
  const float* gamma2 = (const float*)d_in[5];
  const float* beta2  = (const float*)d_in[6];
  const int* rule_in  = (const int*)d_in[7];
  const int* rule_out = (const int*)d_in[8];
  float* out = (float*)d_out;

  int*       gatherT = (int*)d_ws;
  _Float16*  x1h     = (_Float16*)((char*)d_ws + OFF_X1H);
  _Float16*  featsh  = (_Float16*)((char*)d_ws + OFF_FH);
  _Float16*  WB1     = (_Float16*)((char*)d_ws + OFF_WB1);
  _Float16*  WB2     = (_Float16*)((char*)d_ws + OFF_WB2);
  float*     stats   = (float*)((char*)d_ws + OFF_ST);
  // stats: [0:64] sums1, [64:128] sums2

  k_build<<<(KOFF * NVOX + 255) / 256, 256, 0, stream>>>(
      rule_in, rule_out, feats, W1, W2, gatherT, featsh, WB1, WB2, x1h, stats);
  k_conv1m<<<782, 512, 0, stream>>>(featsh, gatherT, (const uint4*)WB1, x1h, stats);
  k_conv2m<<<782, 512, 0, stream>>>(x1h, gatherT, (const uint4*)WB2, out, stats + 64,
                                    stats, gamma1, beta1);
  k_bnrelu2<<<(NVOX * COUT / 4 + 255) / 256, 256, 0, stream>>>(out, stats + 64, gamma2, beta2);
}

// Round 7
// 206.173 us; speedup vs baseline: 1.0806x; 1.0806x over previous
//
#include <hip/hip_runtime.h>

#define NVOX 200000
#define KOFF 27
#define CIN 16
#define CMID 32
#define COUT 32
#define EPSBN 1e-3f
#define PD1 8   // conv1 pipeline depth (proven)
#define PD2 6   // conv2 pipeline depth (proven; 10 spills)

typedef _Float16 f16x8 __attribute__((ext_vector_type(8)));
typedef _Float16 f16x4 __attribute__((ext_vector_type(4)));
typedef float f32x16 __attribute__((ext_vector_type(16)));

// ws layout (bytes):
//   [0, 21,600,000)              gatherT int32[KOFF][NVOX]  (-1 = none; gap-filled in k_build)
//   [21,600,000, 34,400,064)     x1h fp16[(NVOX+1)][32]  (conv1 RAW out; BN1 applied on the fly in conv2)
//   [34,400,064, 40,800,096)     featsh fp16[(NVOX+1)][16] (row NVOX = zeros)
//   [40,800,096, 40,827,744)     WB1 fp16[27][64][8]   B-frags for 32x32x16 (K=16=CIN)
//   [40,827,744, 40,883,040)     WB2 fp16[27][2][64][8] B-frags (K=32 split in 2)
//   [40,883,040, 40,883,552)     stats: sums1[64] | sums2[64]
//   [40,883,552, 53,683,552)     xouth fp16[NVOX][32] (conv2 out, only if ws_size permits)
#define OFF_X1H 21600000
#define OFF_FH  34400064
#define OFF_WB1 40800096
#define OFF_WB2 40827744
#define OFF_ST  40883040
#define OFF_XO  40883552

// One pass: rulebook -> gatherT (-1 gap fill), feats->fp16, weight B-frags,
// zero rows, stats zeroing. rule_out ascending within each k; padding dst = NVOX.
__global__ __launch_bounds__(256) void k_build(const int* __restrict__ rule_in,
                                               const int* __restrict__ rule_out,
                                               const float* __restrict__ feats,
                                               const float* __restrict__ W1,
                                               const float* __restrict__ W2,
                                               int* __restrict__ gatherT,
                                               _Float16* __restrict__ featsh,
                                               _Float16* __restrict__ WB1,
                                               _Float16* __restrict__ WB2,
                                               _Float16* __restrict__ x1h,
                                               float* __restrict__ stats) {
  int e = blockIdx.x * 256 + threadIdx.x;
  if (e < KOFF * NVOX) {
    int k = e / NVOX;
    int pos = e - k * NVOX;
    int dst = rule_out[e];
    int ndst = (pos == NVOX - 1) ? NVOX : rule_out[e + 1];
    int* __restrict__ gk = gatherT + k * NVOX;
    if (dst < NVOX) {
      gk[dst] = rule_in[e];
      if (pos == 0) {
        for (int d = 0; d < dst; ++d) gk[d] = -1;
      }
      for (int d = dst + 1; d < ndst; ++d) gk[d] = -1;
    }
  }
  if (e < NVOX * CIN / 4) {
    float4 f = ((const float4*)feats)[e];
    f16x4 h = {(_Float16)f.x, (_Float16)f.y, (_Float16)f.z, (_Float16)f.w};
    ((f16x4*)featsh)[e] = h;
  }
  if (e < KOFF * 512) {  // WB1: lane l holds W1[k][kk=(l>>5)*8+j][n=l&31]
    int j = e & 7, l = (e >> 3) & 63, k = e >> 9;
    int kk = ((l >> 5) << 3) + j;
    int n = l & 31;
    WB1[e] = (_Float16)W1[(k * CIN + kk) * CMID + n];
  }
  if (e < KOFF * 1024) {  // WB2: f selects K-half
    int j = e & 7, l = (e >> 3) & 63, f = (e >> 9) & 1, k = e >> 10;
    int kk = (f << 4) + ((l >> 5) << 3) + j;
    int n = l & 31;
    WB2[e] = (_Float16)W2[(k * CMID + kk) * COUT + n];
  }
  if (e < CIN) featsh[(size_t)NVOX * CIN + e] = (_Float16)0.f;
  if (e < CMID) x1h[(size_t)NVOX * CMID + e] = (_Float16)0.f;
  if (e < 128) stats[e] = 0.f;
}

// conv1: 32 rows/wave, 1 MFMA (32x32x16, K=16=CIN) per offset.
// Depth-PD1 explicit pipeline; invalid neighbors read the zero row. Fused BN1 stats.
__global__ __launch_bounds__(512, 4) void k_conv1m(const _Float16* __restrict__ featsh,
                                                   const int* __restrict__ gatherT,
                                                   const uint4* __restrict__ WB1,
                                                   _Float16* __restrict__ x1h,
                                                   float* __restrict__ gsums) {
  __shared__ uint4 wlds[KOFF * 64];  // 27,648 B
  __shared__ float lsum[64];
  int tid = threadIdx.x;
  for (int i = tid; i < KOFF * 64; i += 512) wlds[i] = WB1[i];
  if (tid < 64) lsum[tid] = 0.f;
  __syncthreads();

  int lane = tid & 63, wave = tid >> 6;
  int m = lane & 31, h = lane >> 5;
  int rowbase = blockIdx.x * 256 + wave * 32;
  int row = rowbase + m;
  int rowc = (row < NVOX) ? row : (NVOX - 1);

  int idx[KOFF];
#pragma unroll
  for (int k = 0; k < KOFF; ++k) idx[k] = gatherT[k * NVOX + rowc];

  f16x8 A[PD1];
#pragma unroll
  for (int p = 0; p < PD1; ++p) {
    unsigned s = ((unsigned)idx[p] < (unsigned)NVOX) ? (unsigned)idx[p] : (unsigned)NVOX;
    A[p] = *(const f16x8*)(featsh + (size_t)s * CIN + (h << 3));
  }

  f32x16 c;
#pragma unroll
  for (int i = 0; i < 16; ++i) c[i] = 0.f;

#pragma unroll
  for (int k = 0; k < KOFF; ++k) {
    f16x8 a = A[k % PD1];
    if (k + PD1 < KOFF) {
      unsigned s = ((unsigned)idx[k + PD1] < (unsigned)NVOX) ? (unsigned)idx[k + PD1] : (unsigned)NVOX;
      A[k % PD1] = *(const f16x8*)(featsh + (size_t)s * CIN + (h << 3));
    }
    f16x8 b = ((const f16x8*)wlds)[k * 64 + lane];
    c = __builtin_amdgcn_mfma_f32_32x32x16_f16(a, b, c, 0, 0, 0);
  }

  // C layout: col = lane&31 (= channel m), row = (r&3) + 8*(r>>2) + 4*h
  float s0 = 0.f, q0 = 0.f;
#pragma unroll
  for (int r = 0; r < 16; ++r) {
    int grow = rowbase + (r & 3) + ((r >> 2) << 3) + (h << 2);
    float mk = (grow < NVOX) ? 1.f : 0.f;
    float v = c[r] * mk;
    s0 += v; q0 += v * v;
    if (grow < NVOX) x1h[(size_t)grow * CMID + m] = (_Float16)c[r];
  }
  s0 += __shfl_xor(s0, 32, 64);
  q0 += __shfl_xor(q0, 32, 64);
  if (lane < 32) {
    atomicAdd(&lsum[m], s0);
    atomicAdd(&lsum[32 + m], q0);
  }
  __syncthreads();
  if (tid < 64) atomicAdd(&gsums[tid], lsum[tid]);
}

// conv2: 32 rows/wave, 2 MFMAs (K=32) per offset, RAW x1h input. BN1+ReLU fused
// via a DECOUPLED pipeline: at iteration k, BN+mask is applied to the fragment
// for iteration k+1 (its load was issued PD2-1=5 iterations ago and is retired),
// producing pa0/pa1 consumed by the next pair of MFMAs. This keeps the BN VALU
// work OFF the load->MFMA critical chain (R3's consume-time fusion cost +4.3us).
// LDS weight staging kept (R6 removal cost +13us). O16: write fp16 conv2 output
// (halves the epilogue + bnrelu2 stream traffic); fp32 fallback if ws is small.
template <int O16>
__global__ __launch_bounds__(512, 4) void k_conv2m(const _Float16* __restrict__ x1h,
                                                   const int* __restrict__ gatherT,
                                                   const uint4* __restrict__ WB2,
                                                   float* __restrict__ out,
                                                   _Float16* __restrict__ xouth,
                                                   float* __restrict__ gsums,
                                                   const float* __restrict__ sums1,
                                                   const float* __restrict__ gamma1,
                                                   const float* __restrict__ beta1) {
  __shared__ uint4 wlds[KOFF * 128];  // 55,296 B
  __shared__ float lsum[64];
  int tid = threadIdx.x;
  for (int i = tid; i < KOFF * 128; i += 512) wlds[i] = WB2[i];
  if (tid < 64) lsum[tid] = 0.f;

  int lane = tid & 63, wave = tid >> 6;
  int m = lane & 31, h = lane >> 5;

  // BN1 scale/shift for this lane's 16 input channels (fp32 finalize, fp16 apply)
  f16x8 scv0, shv0, scv1, shv1;
  {
    const float inv_n = 1.0f / (float)NVOX;
    int c0 = h << 3;
#pragma unroll
    for (int i = 0; i < 8; ++i) {
      int ca = c0 + i, cb = 16 + c0 + i;
      float mua = sums1[ca] * inv_n;
      float vara = sums1[32 + ca] * inv_n - mua * mua;
      float sa = gamma1[ca] * rsqrtf(vara + EPSBN);
      scv0[i] = (_Float16)sa;
      shv0[i] = (_Float16)(beta1[ca] - mua * sa);
      float mub = sums1[cb] * inv_n;
      float varb = sums1[32 + cb] * inv_n - mub * mub;
      float sb = gamma1[cb] * rsqrtf(varb + EPSBN);
      scv1[i] = (_Float16)sb;
      shv1[i] = (_Float16)(beta1[cb] - mub * sb);
    }
  }
  __syncthreads();

  int rowbase = blockIdx.x * 256 + wave * 32;
  int row = rowbase + m;
  int rowc = (row < NVOX) ? row : (NVOX - 1);

  int idx[KOFF];
#pragma unroll
  for (int k = 0; k < KOFF; ++k) idx[k] = gatherT[k * NVOX + rowc];

  f16x8 A0[PD2], A1[PD2];
#pragma unroll
  for (int p = 0; p < PD2; ++p) {
    unsigned s = ((unsigned)idx[p] < (unsigned)NVOX) ? (unsigned)idx[p] : 0u;
    const _Float16* rp = x1h + (size_t)s * CMID + (h << 3);
    A0[p] = *(const f16x8*)rp;
    A1[p] = *(const f16x8*)(rp + 16);
  }

  f32x16 c;
#pragma unroll
  for (int i = 0; i < 16; ++i) c[i] = 0.f;

  const f16x8 zero8 = (f16x8)(_Float16)0.f;

  // prologue: BN+mask for k=0 (one-time stall on A[0])
  f16x8 pa0, pa1;
  {
    bool v = (unsigned)idx[0] < (unsigned)NVOX;
    f16x8 t0 = A0[0] * scv0 + shv0;
    f16x8 t1 = A1[0] * scv1 + shv1;
    t0 = __builtin_elementwise_max(t0, zero8);
    t1 = __builtin_elementwise_max(t1, zero8);
    pa0 = v ? t0 : zero8;
    pa1 = v ? t1 : zero8;
  }

#pragma unroll
  for (int k = 0; k < KOFF; ++k) {
    f16x8 b0 = ((const f16x8*)wlds)[(k * 2 + 0) * 64 + lane];
    f16x8 b1 = ((const f16x8*)wlds)[(k * 2 + 1) * 64 + lane];
    c = __builtin_amdgcn_mfma_f32_32x32x16_f16(pa0, b0, c, 0, 0, 0);
    c = __builtin_amdgcn_mfma_f32_32x32x16_f16(pa1, b1, c, 0, 0, 0);
    if (k + PD2 < KOFF) {  // refill slot k%PD2 (its value was consumed into pa at k-1)
      unsigned s = ((unsigned)idx[k + PD2] < (unsigned)NVOX) ? (unsigned)idx[k + PD2] : 0u;
      const _Float16* rp = x1h + (size_t)s * CMID + (h << 3);
      A0[k % PD2] = *(const f16x8*)rp;
      A1[k % PD2] = *(const f16x8*)(rp + 16);
    }
    if (k + 1 < KOFF) {  // BN+mask for k+1 from slot (k+1)%PD2 (loaded 5 iters ago)
      bool v = (unsigned)idx[k + 1] < (unsigned)NVOX;
      f16x8 t0 = A0[(k + 1) % PD2] * scv0 + shv0;
      f16x8 t1 = A1[(k + 1) % PD2] * scv1 + shv1;
      t0 = __builtin_elementwise_max(t0, zero8);
      t1 = __builtin_elementwise_max(t1, zero8);
      pa0 = v ? t0 : zero8;
      pa1 = v ? t1 : zero8;
    }
  }

  float s0 = 0.f, q0 = 0.f;
#pragma unroll
  for (int r = 0; r < 16; ++r) {
    int grow = rowbase + (r & 3) + ((r >> 2) << 3) + (h << 2);
    float mk = (grow < NVOX) ? 1.f : 0.f;
    float v = c[r] * mk;
    s0 += v; q0 += v * v;
    if (grow < NVOX) {
      if (O16) xouth[(size_t)grow * COUT + m] = (_Float16)c[r];
      else     out[(size_t)grow * COUT + m] = c[r];
    }
  }
  s0 += __shfl_xor(s0, 32, 64);
  q0 += __shfl_xor(q0, 32, 64);
  if (lane < 32) {
    atomicAdd(&lsum[m], s0);
    atomicAdd(&lsum[32 + m], q0);
  }
  __syncthreads();
  if (tid < 64) atomicAdd(&gsums[tid], lsum[tid]);
}

// BN2+ReLU, fp16 input variant (conv2 wrote xouth): read 12.8MB, write 25.6MB
__global__ __launch_bounds__(256) void k_bnrelu2h(const _Float16* __restrict__ xouth,
                                                  float* __restrict__ out,
                                                  const float* __restrict__ sums,
                                                  const float* __restrict__ gamma,
                                                  const float* __restrict__ beta) {
  int t = blockIdx.x * 256 + threadIdx.x;
  if (t >= NVOX * COUT / 8) return;
  int c = (t & 3) * 8;
  const float inv_n = 1.0f / (float)NVOX;
  float sc[8], sh[8];
#pragma unroll
  for (int i = 0; i < 8; ++i) {
    float mu = sums[c + i] * inv_n;
    float var = sums[32 + c + i] * inv_n - mu * mu;
    float s = gamma[c + i] * rsqrtf(var + EPSBN);
    sc[i] = s; sh[i] = beta[c + i] - mu * s;
  }
  f16x8 v = ((const f16x8*)xouth)[t];
  float4 o0, o1;
  o0.x = fmaxf(fmaf((float)v[0], sc[0], sh[0]), 0.f);
  o0.y = fmaxf(fmaf((float)v[1], sc[1], sh[1]), 0.f);
  o0.z = fmaxf(fmaf((float)v[2], sc[2], sh[2]), 0.f);
  o0.w = fmaxf(fmaf((float)v[3], sc[3], sh[3]), 0.f);
  o1.x = fmaxf(fmaf((float)v[4], sc[4], sh[4]), 0.f);
  o1.y = fmaxf(fmaf((float)v[5], sc[5], sh[5]), 0.f);
  o1.z = fmaxf(fmaf((float)v[6], sc[6], sh[6]), 0.f);
  o1.w = fmaxf(fmaf((float)v[7], sc[7], sh[7]), 0.f);
  ((float4*)out)[t * 2] = o0;
  ((float4*)out)[t * 2 + 1] = o1;
}

// BN2+ReLU in place on fp32 out (fallback when ws has no room for xouth)
__global__ __launch_bounds__(256) void k_bnrelu2(float* __restrict__ out,
                                                 const float* __restrict__ sums,
                                                 const float* __restrict__ gamma,
                                                 const float* __restrict__ beta) {
  int t = blockIdx.x * 256 + threadIdx.x;
  if (t >= NVOX * COUT / 4) return;
  int c = (t & 7) * 4;
  const float inv_n = 1.0f / (float)NVOX;
  float sc[4], sh[4];
#pragma unroll
  for (int i = 0; i < 4; ++i) {
    float mu = sums[c + i] * inv_n;
    float var = sums[32 + c + i] * inv_n - mu * mu;
    float s = gamma[c + i] * rsqrtf(var + EPSBN);
    sc[i] = s; sh[i] = beta[c + i] - mu * s;
  }
  float4* p = (float4*)out + t;
  float4 v = *p;
  v.x = fmaxf(fmaf(v.x, sc[0], sh[0]), 0.f);
  v.y = fmaxf(fmaf(v.y, sc[1], sh[1]), 0.f);
  v.z = fmaxf(fmaf(v.z, sc[2], sh[2]), 0.f);
  v.w = fmaxf(fmaf(v.w, sc[3], sh[3]), 0.f);
  *p = v;
}

extern "C" void kernel_launch(void* const* d_in, const int* in_sizes, int n_in,
                              void* d_out, int out_size, void* d_ws, size_t ws_size,
                              hipStream_t stream) {
  const float* feats  = (const float*)d_in[0];
  const float* W1     = (const float*)d_in[1];
  const float* gamma1 = (const float*)d_in[2];
  const float* beta1  = (const float*)d_in[3];
  const float* W2     = (const float*)d_in[4];
  const float* gamma2 = (const float*)d_in[5];
  const float* beta2  = (const float*)d_in[6];
  const int* rule_in  = (const int*)d_in[7];
  const int* rule_out = (const int*)d_in[8];
  float* out = (float*)d_out;

  int*       gatherT = (int*)d_ws;
  _Float16*  x1h     = (_Float16*)((char*)d_ws + OFF_X1H);
  _Float16*  featsh  = (_Float16*)((char*)d_ws + OFF_FH);
  _Float16*  WB1     = (_Float16*)((char*)d_ws + OFF_WB1);
  _Float16*  WB2     = (_Float16*)((char*)d_ws + OFF_WB2);
  float*     stats   = (float*)((char*)d_ws + OFF_ST);
  _Float16*  xouth   = (_Float16*)((char*)d_ws + OFF_XO);
  // stats: [0:64] sums1, [64:128] sums2

  bool o16 = ws_size >= (size_t)OFF_XO + (size_t)NVOX * COUT * sizeof(_Float16);

  k_build<<<(KOFF * NVOX + 255) / 256, 256, 0, stream>>>(
      rule_in, rule_out, feats, W1, W2, gatherT, featsh, WB1, WB2, x1h, stats);
  k_conv1m<<<782, 512, 0, stream>>>(featsh, gatherT, (const uint4*)WB1, x1h, stats);
  if (o16) {
    k_conv2m<1><<<782, 512, 0, stream>>>(x1h, gatherT, (const uint4*)WB2, out, xouth,
                                         stats + 64, stats, gamma1, beta1);
    k_bnrelu2h<<<(NVOX * COUT / 8 + 255) / 256, 256, 0, stream>>>(
        xouth, out, stats + 64, gamma2, beta2);
  } else {
    k_conv2m<0><<<782, 512, 0, stream>>>(x1h, gatherT, (const uint4*)WB2, out, xouth,
                                         stats + 64, stats, gamma1, beta1);
    k_bnrelu2<<<(NVOX * COUT / 4 + 255) / 256, 256, 0, stream>>>(
        out, stats + 64, gamma2, beta2);
  }
}